// Round 10
// baseline (589.225 us; speedup 1.0000x reference)
//
#include <hip/hip_runtime.h>

#define N_NODES 100000
#define N_EDGES 1600000
#define IN_CH 128
#define HID 256
#define OUT_CH 128
#define N_GRAPHS 2048

#define NBUK 391          // ceil(N_NODES / 256)
#define CHUNK 8192        // edges per binning block

typedef __attribute__((ext_vector_type(8))) short bf16x8;
typedef __attribute__((ext_vector_type(4))) float f32x4;
typedef __attribute__((ext_vector_type(2))) float f32x2;

__device__ inline unsigned short f2b(float f) {  // RNE fp32 -> bf16
    unsigned int u = __builtin_bit_cast(unsigned int, f);
    u = (u + 0x7FFF + ((u >> 16) & 1)) >> 16;
    return (unsigned short)u;
}
__device__ inline float b2f(unsigned short h) {
    unsigned int u = (unsigned int)h << 16;
    return __builtin_bit_cast(float, u);
}

// async global->LDS, 16 B per lane; dst is wave-uniform base, HW adds lane*16
#define GLOAD_LDS16(gsrc, ldst)                                                   \
    __builtin_amdgcn_global_load_lds(                                             \
        (const __attribute__((address_space(1))) void*)(gsrc),                    \
        (__attribute__((address_space(3))) void*)(ldst), 16, 0, 0)

// ---------------------------------------------------------------- scans (for bucket counts)
#define SCAN_ITEMS 8
#define SCAN_TILE (256 * SCAN_ITEMS)

__global__ void scan1_k(const int* __restrict__ in, int* __restrict__ out,
                        int* __restrict__ bsums, int n) {
    __shared__ int wsum[4];
    int base = blockIdx.x * SCAN_TILE + (int)threadIdx.x * SCAN_ITEMS;
    int v[SCAN_ITEMS];
    int s = 0;
    #pragma unroll
    for (int i = 0; i < SCAN_ITEMS; ++i) {
        v[i] = (base + i < n) ? in[base + i] : 0;
        s += v[i];
    }
    int lane = threadIdx.x & 63, wid = threadIdx.x >> 6;
    int incl = s;
    #pragma unroll
    for (int off = 1; off < 64; off <<= 1) {
        int t = __shfl_up(incl, off, 64);
        if (lane >= off) incl += t;
    }
    if (lane == 63) wsum[wid] = incl;
    __syncthreads();
    int wprefix = 0;
    #pragma unroll
    for (int w = 0; w < 4; ++w)
        if (w < wid) wprefix += wsum[w];
    int run = wprefix + incl - s;
    #pragma unroll
    for (int i = 0; i < SCAN_ITEMS; ++i) {
        if (base + i < n) out[base + i] = run;
        run += v[i];
    }
    if (threadIdx.x == 255) bsums[blockIdx.x] = wprefix + incl;
}

__global__ void scan2_k(int* __restrict__ bsums, int nb, int* __restrict__ total) {
    __shared__ int wsum[4];
    int v = ((int)threadIdx.x < nb) ? bsums[threadIdx.x] : 0;
    int lane = threadIdx.x & 63, wid = threadIdx.x >> 6;
    int incl = v;
    #pragma unroll
    for (int off = 1; off < 64; off <<= 1) {
        int t = __shfl_up(incl, off, 64);
        if (lane >= off) incl += t;
    }
    if (lane == 63) wsum[wid] = incl;
    __syncthreads();
    int wprefix = 0;
    #pragma unroll
    for (int w = 0; w < 4; ++w)
        if (w < wid) wprefix += wsum[w];
    if ((int)threadIdx.x < nb) bsums[threadIdx.x] = wprefix + incl - v;
    if (threadIdx.x == 255) *total = wprefix + incl;
}

// ---------------------------------------------------------------- bucketed CSR build
__global__ void bucket_count_k(const int* __restrict__ dst, int* __restrict__ bcnt, int E) {
    __shared__ int cnt[NBUK];
    int tid = threadIdx.x;
    for (int i = tid; i < NBUK; i += 256) cnt[i] = 0;
    __syncthreads();
    int e0 = blockIdx.x * CHUNK;
    int eend = min(e0 + CHUNK, E);
    for (int e = e0 + tid; e < eend; e += 256)
        atomicAdd(&cnt[dst[e] >> 8], 1);
    __syncthreads();
    for (int i = tid; i < NBUK; i += 256)
        if (cnt[i]) atomicAdd(&bcnt[i], cnt[i]);
}

__global__ void bin_scatter_k(const int* __restrict__ src, const int* __restrict__ dst,
                              const int* __restrict__ bbase, int* __restrict__ bcur,
                              uint2* __restrict__ staging, int E) {
    __shared__ int cnt[NBUK];
    __shared__ int gbase[NBUK];
    int tid = threadIdx.x;
    for (int i = tid; i < NBUK; i += 256) cnt[i] = 0;
    __syncthreads();
    int e0 = blockIdx.x * CHUNK;
    int eend = min(e0 + CHUNK, E);
    for (int e = e0 + tid; e < eend; e += 256)
        atomicAdd(&cnt[dst[e] >> 8], 1);
    __syncthreads();
    for (int i = tid; i < NBUK; i += 256) {
        int c = cnt[i];
        gbase[i] = c ? (bbase[i] + atomicAdd(&bcur[i], c)) : 0;
        cnt[i] = 0;  // reuse as local cursor
    }
    __syncthreads();
    for (int e = e0 + tid; e < eend; e += 256) {
        int d = dst[e];
        int b = d >> 8;
        int l = atomicAdd(&cnt[b], 1);
        uint2 p; p.x = (unsigned)src[e]; p.y = (unsigned)d;
        staging[(size_t)gbase[b] + l] = p;
    }
}

__global__ void csr_build_k(const uint2* __restrict__ staging, const int* __restrict__ bbase,
                            int* __restrict__ row_ofs, int* __restrict__ csr) {
    __shared__ int ldeg[256];
    __shared__ int lofs[256];
    __shared__ int wsum[4];
    int b = blockIdx.x, tid = threadIdx.x;
    int base = bbase[b];
    int cnt = bbase[b + 1] - base;
    ldeg[tid] = 0;
    __syncthreads();
    const uint2* sp = staging + base;
    for (int i = tid; i < cnt; i += 256)
        atomicAdd(&ldeg[sp[i].y & 255], 1);
    __syncthreads();
    int v = ldeg[tid];
    int lane = tid & 63, wid = tid >> 6;
    int incl = v;
    #pragma unroll
    for (int off = 1; off < 64; off <<= 1) {
        int t = __shfl_up(incl, off, 64);
        if (lane >= off) incl += t;
    }
    if (lane == 63) wsum[wid] = incl;
    __syncthreads();
    int wprefix = 0;
    #pragma unroll
    for (int w = 0; w < 4; ++w)
        if (w < wid) wprefix += wsum[w];
    int excl = wprefix + incl - v;
    lofs[tid] = excl;
    int node = b * 256 + tid;
    if (node < N_NODES) row_ofs[node] = base + excl;
    if (b == NBUK - 1 && tid == 0) row_ofs[N_NODES] = N_EDGES;
    ldeg[tid] = 0;  // reuse as cursor
    __syncthreads();
    for (int i = tid; i < cnt; i += 256) {
        uint2 p = sp[i];
        int d = (int)p.y & 255;
        int pos = atomicAdd(&ldeg[d], 1);
        csr[base + lofs[d] + pos] = (int)p.x;
    }
}

// gofs[g] = lower_bound(batch, g)  (batch sorted); gofs[G] = n
__global__ void gofs_search_k(const int* __restrict__ batch, int* __restrict__ gofs,
                              int n, int G) {
    int g = blockIdx.x * blockDim.x + threadIdx.x;
    if (g > G) return;
    if (g == G) { gofs[G] = n; return; }
    int lo = 0, hi = n;
    while (lo < hi) {
        int mid = (lo + hi) >> 1;
        if (batch[mid] < g) lo = mid + 1; else hi = mid;
    }
    gofs[g] = lo;
}

// ---------------------------------------------------------------- converts
__global__ void wt_concat_k(const float* __restrict__ Wl, const float* __restrict__ Wr,
                            unsigned short* __restrict__ out, int K1, int K2, int N) {
    int idx = blockIdx.x * blockDim.x + threadIdx.x;
    int KT = K1 + K2;
    if (idx >= N * KT) return;
    int n = idx / KT, k = idx % KT;
    float v = (k < K1) ? Wl[(size_t)k * N + n] : Wr[(size_t)(k - K1) * N + n];
    out[idx] = f2b(v);
}

// fp32 -> (bf16, fp8) in one pass. Thread handles 8 floats.
__global__ void f2b8_k(const float* __restrict__ in, unsigned short* __restrict__ outb,
                       unsigned char* __restrict__ out8, size_t n8) {
    size_t i = (size_t)blockIdx.x * blockDim.x + threadIdx.x;
    if (i >= n8) return;
    float4 a = ((const float4*)in)[i * 2];
    float4 b = ((const float4*)in)[i * 2 + 1];
    unsigned short ob[8];
    ob[0] = f2b(a.x); ob[1] = f2b(a.y); ob[2] = f2b(a.z); ob[3] = f2b(a.w);
    ob[4] = f2b(b.x); ob[5] = f2b(b.y); ob[6] = f2b(b.z); ob[7] = f2b(b.w);
    ((uint4*)outb)[i] = *(const uint4*)ob;
    int w0 = 0, w1 = 0;
    w0 = __builtin_amdgcn_cvt_pk_fp8_f32(a.x, a.y, w0, false);
    w0 = __builtin_amdgcn_cvt_pk_fp8_f32(a.z, a.w, w0, true);
    w1 = __builtin_amdgcn_cvt_pk_fp8_f32(b.x, b.y, w1, false);
    w1 = __builtin_amdgcn_cvt_pk_fp8_f32(b.z, b.w, w1, true);
    uint2 o8; o8.x = (unsigned int)w0; o8.y = (unsigned int)w1;
    ((uint2*)out8)[i] = o8;
}

// bf16 -> fp8 e4m3 (HW cvt). Each thread: 16 bf16 in (32B) -> 16 fp8 out (16B).
__global__ void b2f8_k(const unsigned short* __restrict__ in, unsigned char* __restrict__ out,
                       size_t n16) {
    size_t i = (size_t)blockIdx.x * blockDim.x + threadIdx.x;
    if (i >= n16) return;
    uint4 v0 = ((const uint4*)in)[i * 2];
    uint4 v1 = ((const uint4*)in)[i * 2 + 1];
    const unsigned int* q = (const unsigned int*)&v0;
    const unsigned int* r = (const unsigned int*)&v1;
    uint4 o;
    unsigned int* po = (unsigned int*)&o;
    #pragma unroll
    for (int t = 0; t < 2; ++t) {
        int w = 0;
        w = __builtin_amdgcn_cvt_pk_fp8_f32(b2f((unsigned short)(q[t * 2] & 0xFFFF)),
                                            b2f((unsigned short)(q[t * 2] >> 16)), w, false);
        w = __builtin_amdgcn_cvt_pk_fp8_f32(b2f((unsigned short)(q[t * 2 + 1] & 0xFFFF)),
                                            b2f((unsigned short)(q[t * 2 + 1] >> 16)), w, true);
        po[t] = (unsigned int)w;
    }
    #pragma unroll
    for (int t = 0; t < 2; ++t) {
        int w = 0;
        w = __builtin_amdgcn_cvt_pk_fp8_f32(b2f((unsigned short)(r[t * 2] & 0xFFFF)),
                                            b2f((unsigned short)(r[t * 2] >> 16)), w, false);
        w = __builtin_amdgcn_cvt_pk_fp8_f32(b2f((unsigned short)(r[t * 2 + 1] & 0xFFFF)),
                                            b2f((unsigned short)(r[t * 2 + 1] >> 16)), w, true);
        po[2 + t] = (unsigned int)w;
    }
    ((uint4*)out)[i] = o;
}

// ---------------------------------------------------------------- mean aggregation
// fp8 in [n,C] -> bf16 mean out [n,C]. One wave per node; GL=C/16 lanes x 16B per
// gather, NG=64/GL edge-groups, 2x unroll. Cross-group shfl_xor reduce.
template <int C>
__global__ void agg_f8_k(const unsigned char* __restrict__ X8, const int* __restrict__ row_ofs,
                         const int* __restrict__ csr, unsigned short* __restrict__ out, int n) {
    constexpr int GL = C / 16;
    constexpr int NG = 64 / GL;
    int w = (int)((blockIdx.x * blockDim.x + threadIdx.x) >> 6);
    int lane = threadIdx.x & 63;
    if (w >= n) return;
    int g = lane / GL, il = lane % GL;
    int s = row_ofs[w], e = row_ofs[w + 1];
    float a[16];
    #pragma unroll
    for (int t = 0; t < 16; ++t) a[t] = 0.f;

    int j = s + g;
    for (; j + NG < e; j += 2 * NG) {
        int i0 = csr[j], i1 = csr[j + NG];
        uint4 r0 = *(const uint4*)&X8[(size_t)i0 * C + il * 16];
        uint4 r1 = *(const uint4*)&X8[(size_t)i1 * C + il * 16];
        const unsigned int* q0 = (const unsigned int*)&r0;
        const unsigned int* q1 = (const unsigned int*)&r1;
        #pragma unroll
        for (int t = 0; t < 4; ++t) {
            f32x2 lo = __builtin_amdgcn_cvt_pk_f32_fp8(q0[t], false);
            f32x2 hi = __builtin_amdgcn_cvt_pk_f32_fp8(q0[t], true);
            a[t * 4 + 0] += lo.x; a[t * 4 + 1] += lo.y;
            a[t * 4 + 2] += hi.x; a[t * 4 + 3] += hi.y;
        }
        #pragma unroll
        for (int t = 0; t < 4; ++t) {
            f32x2 lo = __builtin_amdgcn_cvt_pk_f32_fp8(q1[t], false);
            f32x2 hi = __builtin_amdgcn_cvt_pk_f32_fp8(q1[t], true);
            a[t * 4 + 0] += lo.x; a[t * 4 + 1] += lo.y;
            a[t * 4 + 2] += hi.x; a[t * 4 + 3] += hi.y;
        }
    }
    if (j < e) {
        int i0 = csr[j];
        uint4 r0 = *(const uint4*)&X8[(size_t)i0 * C + il * 16];
        const unsigned int* q0 = (const unsigned int*)&r0;
        #pragma unroll
        for (int t = 0; t < 4; ++t) {
            f32x2 lo = __builtin_amdgcn_cvt_pk_f32_fp8(q0[t], false);
            f32x2 hi = __builtin_amdgcn_cvt_pk_f32_fp8(q0[t], true);
            a[t * 4 + 0] += lo.x; a[t * 4 + 1] += lo.y;
            a[t * 4 + 2] += hi.x; a[t * 4 + 3] += hi.y;
        }
    }

    #pragma unroll
    for (int m = GL; m < 64; m <<= 1)
        #pragma unroll
        for (int t = 0; t < 16; ++t) a[t] += __shfl_xor(a[t], m, 64);

    if (g == 0) {
        float inv = 1.0f / (float)max(e - s, 1);
        uint4 o0, o1;
        unsigned short* p0 = (unsigned short*)&o0;
        unsigned short* p1 = (unsigned short*)&o1;
        #pragma unroll
        for (int t = 0; t < 8; ++t) p0[t] = f2b(a[t] * inv);
        #pragma unroll
        for (int t = 0; t < 8; ++t) p1[t] = f2b(a[8 + t] * inv);
        *(uint4*)&out[(size_t)w * C + il * 16] = o0;
        *(uint4*)&out[(size_t)w * C + il * 16 + 8] = o1;
    }
}

// pool: bf16 input [N,256] -> fp32 pooled [G,256]; one wave per graph
__global__ void pool_mean_k(const unsigned short* __restrict__ H, const int* __restrict__ gofs,
                            float* __restrict__ pooled, int G) {
    int g = (int)((blockIdx.x * blockDim.x + threadIdx.x) >> 6);
    int lane = threadIdx.x & 63;
    if (g >= G) return;
    int s = gofs[g], e = gofs[g + 1];
    float a0 = 0.f, a1 = 0.f, a2 = 0.f, a3 = 0.f;
    for (int r = s; r < e; ++r) {
        ushort4 t = ((const ushort4*)(H + (size_t)r * HID))[lane];
        a0 += b2f(t.x); a1 += b2f(t.y); a2 += b2f(t.z); a3 += b2f(t.w);
    }
    float inv = 1.0f / (float)max(e - s, 1);
    float4 o; o.x = a0 * inv; o.y = a1 * inv; o.z = a2 * inv; o.w = a3 * inv;
    ((float4*)(pooled + (size_t)g * HID))[lane] = o;
}

// ---------------------------------------------------------------- bf16 MFMA GEMM
// 128x128 tile, 4 waves 2x2, each wave 4x4 frags of 16x16x32, BK=32.
// Triple-buffered LDS, 2-tile-ahead global_load_lds prefetch held across raw
// barriers. LDS tiles stored K-CHUNK-MAJOR: element A[row][k] at short offset
// (row>>6)*2048 + (k>>3)*512 + (row&63)*8 + (k&7)  -> frag reads are
// lane-consecutive 16B (2-way bank aliasing = free) instead of 8-way conflicts.
__launch_bounds__(256)
__global__ void mfma_gemm_k(const unsigned short* __restrict__ A1, int K1,
                            const unsigned short* __restrict__ A2, int K2,
                            const unsigned short* __restrict__ Bt,
                            const float* __restrict__ bias, int M, int Nfull,
                            void* __restrict__ Cptr, int c_bf16, int do_relu) {
    __shared__ short ldsA[3 * 4096];
    __shared__ short ldsB[3 * 4096];
    int tid = threadIdx.x, lane = tid & 63;
    int wid = tid >> 6, wm = wid >> 1, wn = wid & 1;
    int row0 = blockIdx.x * 128, col0 = blockIdx.y * 128;
    int q = lane >> 4, l15 = lane & 15;
    int KT = K1 + K2;
    int nk = KT / 32;

    // staging: thread t = (chunk=wid, row=lane) per 64-row half; DMA writes
    // LDS byte t*16 -> chunk-major layout [half][chunk][row] achieved.
    auto stage = [&](int t) {
        int kt = t * 32;
        const unsigned short* Asrc; int kk, Ks;
        if (kt < K1) { Asrc = A1; kk = kt; Ks = K1; }
        else         { Asrc = A2; kk = kt - K1; Ks = K2; }
        int buf = t % 3;
        short* bA = ldsA + buf * 4096;
        short* bB = ldsB + buf * 4096;
        #pragma unroll
        for (int h = 0; h < 2; ++h) {
            int r = h * 64 + lane;
            int gr = min(row0 + r, M - 1);
            GLOAD_LDS16(Asrc + (size_t)gr * Ks + kk + wid * 8, bA + h * 2048 + wid * 512);
            GLOAD_LDS16(Bt + (size_t)(col0 + r) * KT + kt + wid * 8, bB + h * 2048 + wid * 512);
        }
    };

    f32x4 acc[4][4] = {};

    stage(0);
    stage(1);
    stage(2);

    for (int t = 0; t < nk; ++t) {
        if (t < nk - 2)       asm volatile("s_waitcnt vmcnt(8)" ::: "memory");
        else if (t == nk - 2) asm volatile("s_waitcnt vmcnt(4)" ::: "memory");
        else                  asm volatile("s_waitcnt vmcnt(0)" ::: "memory");
        asm volatile("s_barrier" ::: "memory");   // tile t visible to all waves

        int buf = t % 3;
        const short* bA = ldsA + buf * 4096;
        const short* bB = ldsB + buf * 4096;
        bf16x8 af[4], bfr[4];
        #pragma unroll
        for (int i = 0; i < 4; ++i)
            af[i] = *(const bf16x8*)&bA[wm * 2048 + q * 512 + (i * 16 + l15) * 8];
        #pragma unroll
        for (int j = 0; j < 4; ++j)
            bfr[j] = *(const bf16x8*)&bB[wn * 2048 + q * 512 + (j * 16 + l15) * 8];
        #pragma unroll
        for (int i = 0; i < 4; ++i)
            #pragma unroll
            for (int j = 0; j < 4; ++j)
                acc[i][j] = __builtin_amdgcn_mfma_f32_16x16x32_bf16(af[i], bfr[j], acc[i][j], 0, 0, 0);

        asm volatile("s_barrier" ::: "memory");   // all waves done reading buf
        if (t + 3 < nk) stage(t + 3);             // refill the buffer just consumed
    }

    // epilogue: D layout col=lane&15, row=quad*4+reg
    #pragma unroll
    for (int i = 0; i < 4; ++i) {
        #pragma unroll
        for (int reg = 0; reg < 4; ++reg) {
            int r = row0 + wm * 64 + i * 16 + q * 4 + reg;
            if (r < M) {
                #pragma unroll
                for (int j = 0; j < 4; ++j) {
                    int cc = col0 + wn * 64 + j * 16 + l15;
                    float v = acc[i][j][reg] + bias[cc];
                    if (do_relu) v = fmaxf(v, 0.f);
                    if (c_bf16) ((unsigned short*)Cptr)[(size_t)r * Nfull + cc] = f2b(v);
                    else        ((float*)Cptr)[(size_t)r * Nfull + cc] = v;
                }
            }
        }
    }
}

// ---------------------------------------------------------------- fp32 GEMM (head only)
#define BM_ 64
#define BK_ 16

template <int BN_>
__launch_bounds__(256)
__global__ void gemm2_k(const float* __restrict__ A1, const float* __restrict__ B1, int K1,
                        const float* __restrict__ bias, float* __restrict__ C,
                        int M, int N, int do_relu) {
    constexpr int TCOLS = BN_ / 8;
    constexpr int TROWS = 256 / TCOLS;
    constexpr int TM = BM_ / TROWS;
    __shared__ float As[BK_][BM_ + 4];
    __shared__ float Bs[BK_][BN_ + 4];
    int tid = threadIdx.x;
    int row0 = blockIdx.x * BM_;
    int col0 = blockIdx.y * BN_;
    int tx = tid % TCOLS, ty = tid / TCOLS;

    float acc[TM][8];
    #pragma unroll
    for (int i = 0; i < TM; ++i)
        #pragma unroll
        for (int j = 0; j < 8; ++j) acc[i][j] = 0.f;

    int ar = tid >> 2;
    int ak = (tid & 3) * 4;

    for (int kt = 0; kt < K1; kt += BK_) {
        {
            int r = row0 + ar;
            int rc = min(r, M - 1);
            float4 v = *(const float4*)(A1 + (size_t)rc * K1 + kt + ak);
            As[ak + 0][ar] = v.x;
            As[ak + 1][ar] = v.y;
            As[ak + 2][ar] = v.z;
            As[ak + 3][ar] = v.w;
        }
        {
            #pragma unroll
            for (int h = 0; h < BN_ / 64; ++h) {
                int idx = h * 256 + tid;
                int kr = idx / (BN_ / 4);
                int c4 = idx % (BN_ / 4);
                float4 v = *(const float4*)(B1 + (size_t)(kt + kr) * N + col0 + c4 * 4);
                *(float4*)&Bs[kr][c4 * 4] = v;
            }
        }
        __syncthreads();

        #pragma unroll
        for (int k = 0; k < BK_; ++k) {
            float a[TM], b[8];
            #pragma unroll
            for (int v = 0; v < TM / 4; ++v)
                *(float4*)&a[v * 4] = *(const float4*)&As[k][ty * TM + v * 4];
            *(float4*)&b[0] = *(const float4*)&Bs[k][tx * 8];
            *(float4*)&b[4] = *(const float4*)&Bs[k][tx * 8 + 4];
            #pragma unroll
            for (int i = 0; i < TM; ++i)
                #pragma unroll
                for (int j = 0; j < 8; ++j) acc[i][j] = fmaf(a[i], b[j], acc[i][j]);
        }
        __syncthreads();
    }

    float bv[8];
    #pragma unroll
    for (int j = 0; j < 8; ++j) bv[j] = bias[col0 + tx * 8 + j];
    #pragma unroll
    for (int i = 0; i < TM; ++i) {
        int r = row0 + ty * TM + i;
        if (r < M) {
            float* cp = C + (size_t)r * N + col0 + tx * 8;
            float o[8];
            #pragma unroll
            for (int j = 0; j < 8; ++j) {
                float v = acc[i][j] + bv[j];
                o[j] = do_relu ? fmaxf(v, 0.f) : v;
            }
            *(float4*)(cp + 0) = *(float4*)&o[0];
            *(float4*)(cp + 4) = *(float4*)&o[4];
        }
    }
}

// ---------------------------------------------------------------- launcher
extern "C" void kernel_launch(void* const* d_in, const int* in_sizes, int n_in,
                              void* d_out, int out_size, void* d_ws, size_t ws_size,
                              hipStream_t stream) {
    const float* x    = (const float*)d_in[0];
    const int*   ei   = (const int*)d_in[1];
    const int*   batch= (const int*)d_in[2];
    const float* W1l  = (const float*)d_in[3];
    const float* b1   = (const float*)d_in[4];
    const float* W1r  = (const float*)d_in[5];
    const float* W2l  = (const float*)d_in[6];
    const float* b2   = (const float*)d_in[7];
    const float* W2r  = (const float*)d_in[8];
    const float* W3   = (const float*)d_in[9];
    const float* b3   = (const float*)d_in[10];
    const float* W4   = (const float*)d_in[11];
    const float* b4   = (const float*)d_in[12];
    float* out = (float*)d_out;

    const int N = N_NODES, E = N_EDGES, G = N_GRAPHS;
    const int* src = ei;
    const int* dst = ei + E;

    char* ws = (char*)d_ws;
    size_t off = 0;
    auto alloc = [&](size_t bytes) -> char* {
        off = (off + 255) & ~(size_t)255;
        char* p = ws + off;
        off += bytes;
        return p;
    };
    int* bcnt    = (int*)alloc((size_t)NBUK * 4);
    int* bcur    = (int*)alloc((size_t)NBUK * 4);
    size_t zero_span = (size_t)((char*)(bcur + NBUK) - (char*)bcnt);
    int* bbase   = (int*)alloc((size_t)(NBUK + 1) * 4);
    int* bsums   = (int*)alloc(256 * 4);
    int* row_ofs = (int*)alloc((size_t)(N + 1) * 4);
    int* gofs    = (int*)alloc((size_t)(G + 1) * 4);
    uint2* staging = (uint2*)alloc((size_t)E * 8);
    int* csr     = (int*)alloc((size_t)E * 4);
    unsigned short* xb    = (unsigned short*)alloc((size_t)N * IN_CH * 2);
    unsigned short* mean1 = (unsigned short*)alloc((size_t)N * IN_CH * 2);
    unsigned short* h1    = (unsigned short*)alloc((size_t)N * HID * 2);
    unsigned short* mean2 = (unsigned short*)alloc((size_t)N * HID * 2);
    unsigned short* h2    = xb;  // xb+mean1 contiguous span reused for h2 [N,256]
    unsigned char*  x8    = (unsigned char*)alloc((size_t)N * IN_CH);
    unsigned char*  h1f8  = (unsigned char*)alloc((size_t)N * HID);
    unsigned short* W1T   = (unsigned short*)alloc((size_t)HID * (IN_CH + IN_CH) * 2);
    unsigned short* W2T   = (unsigned short*)alloc((size_t)HID * (HID + HID) * 2);
    float* pooled = (float*)alloc((size_t)G * HID * 4);
    float* hidden = (float*)alloc((size_t)G * HID * 4);
    (void)ws_size;

    hipMemsetAsync(bcnt, 0, zero_span, stream);

    const int EB = (E + CHUNK - 1) / CHUNK;  // 196
    bucket_count_k<<<EB, 256, 0, stream>>>(dst, bcnt, E);
    scan1_k<<<1, 256, 0, stream>>>(bcnt, bbase, bsums, NBUK);
    scan2_k<<<1, 256, 0, stream>>>(bsums, 1, bbase + NBUK);
    bin_scatter_k<<<EB, 256, 0, stream>>>(src, dst, bbase, bcur, staging, E);
    csr_build_k<<<NBUK, 256, 0, stream>>>(staging, bbase, row_ofs, csr);

    gofs_search_k<<<(G + 256) / 256, 256, 0, stream>>>(batch, gofs, N, G);

    wt_concat_k<<<(HID * 2 * IN_CH + 255) / 256, 256, 0, stream>>>(W1l, W1r, W1T, IN_CH, IN_CH, HID);
    wt_concat_k<<<(HID * 2 * HID + 255) / 256, 256, 0, stream>>>(W2l, W2r, W2T, HID, HID, HID);
    f2b8_k<<<(int)(((size_t)N * IN_CH / 8 + 255) / 256), 256, 0, stream>>>(
        x, xb, x8, (size_t)N * IN_CH / 8);

    const int MB = (N + 127) / 128;

    // layer 1: mean1 = mean-agg(x8) [fp8 gather]; h1 = relu([mean1|xb] @ W1T^T + b1)
    agg_f8_k<IN_CH><<<(N + 3) / 4, 256, 0, stream>>>(x8, row_ofs, csr, mean1, N);
    mfma_gemm_k<<<dim3(MB, HID / 128), 256, 0, stream>>>(
        mean1, IN_CH, xb, IN_CH, W1T, b1, N, HID, h1, 1, 1);

    // fp8 mirror of h1 for the layer-2 gather
    b2f8_k<<<(int)(((size_t)N * HID / 16 + 255) / 256), 256, 0, stream>>>(
        h1, h1f8, (size_t)N * HID / 16);

    // layer 2: mean2 = mean-agg(h1f8) [fp8 gather]; h2 = relu([mean2|h1] @ W2T^T + b2)
    agg_f8_k<HID><<<(N + 3) / 4, 256, 0, stream>>>(h1f8, row_ofs, csr, mean2, N);
    mfma_gemm_k<<<dim3(MB, HID / 128), 256, 0, stream>>>(
        mean2, HID, h1, HID, W2T, b2, N, HID, h2, 1, 1);

    // global mean pool (bf16 in, fp32 out)
    pool_mean_k<<<(G + 3) / 4, 256, 0, stream>>>(h2, gofs, pooled, G);

    // MLP head (fp32)
    gemm2_k<HID><<<dim3(G / BM_, 1), 256, 0, stream>>>(
        pooled, W3, HID, b3, hidden, G, HID, 1);
    gemm2_k<OUT_CH><<<dim3(G / BM_, 1), 256, 0, stream>>>(
        hidden, W4, HID, b4, out, G, OUT_CH, 0);
}

// Round 11
// 585.225 us; speedup vs baseline: 1.0068x; 1.0068x over previous
//
#include <hip/hip_runtime.h>

#define N_NODES 100000
#define N_EDGES 1600000
#define IN_CH 128
#define HID 256
#define OUT_CH 128
#define N_GRAPHS 2048

#define NBUK 391          // ceil(N_NODES / 256)
#define CHUNK 8192        // edges per binning block

typedef __attribute__((ext_vector_type(8))) short bf16x8;
typedef __attribute__((ext_vector_type(4))) float f32x4;
typedef __attribute__((ext_vector_type(2))) float f32x2;

__device__ inline unsigned short f2b(float f) {  // RNE fp32 -> bf16
    unsigned int u = __builtin_bit_cast(unsigned int, f);
    u = (u + 0x7FFF + ((u >> 16) & 1)) >> 16;
    return (unsigned short)u;
}
__device__ inline float b2f(unsigned short h) {
    unsigned int u = (unsigned int)h << 16;
    return __builtin_bit_cast(float, u);
}

// async global->LDS, 16 B per lane; dst is wave-uniform base, HW adds lane*16
#define GLOAD_LDS16(gsrc, ldst)                                                   \
    __builtin_amdgcn_global_load_lds(                                             \
        (const __attribute__((address_space(1))) void*)(gsrc),                    \
        (__attribute__((address_space(3))) void*)(ldst), 16, 0, 0)

// ---------------------------------------------------------------- scans (for bucket counts)
#define SCAN_ITEMS 8
#define SCAN_TILE (256 * SCAN_ITEMS)

__global__ void scan1_k(const int* __restrict__ in, int* __restrict__ out,
                        int* __restrict__ bsums, int n) {
    __shared__ int wsum[4];
    int base = blockIdx.x * SCAN_TILE + (int)threadIdx.x * SCAN_ITEMS;
    int v[SCAN_ITEMS];
    int s = 0;
    #pragma unroll
    for (int i = 0; i < SCAN_ITEMS; ++i) {
        v[i] = (base + i < n) ? in[base + i] : 0;
        s += v[i];
    }
    int lane = threadIdx.x & 63, wid = threadIdx.x >> 6;
    int incl = s;
    #pragma unroll
    for (int off = 1; off < 64; off <<= 1) {
        int t = __shfl_up(incl, off, 64);
        if (lane >= off) incl += t;
    }
    if (lane == 63) wsum[wid] = incl;
    __syncthreads();
    int wprefix = 0;
    #pragma unroll
    for (int w = 0; w < 4; ++w)
        if (w < wid) wprefix += wsum[w];
    int run = wprefix + incl - s;
    #pragma unroll
    for (int i = 0; i < SCAN_ITEMS; ++i) {
        if (base + i < n) out[base + i] = run;
        run += v[i];
    }
    if (threadIdx.x == 255) bsums[blockIdx.x] = wprefix + incl;
}

__global__ void scan2_k(int* __restrict__ bsums, int nb, int* __restrict__ total) {
    __shared__ int wsum[4];
    int v = ((int)threadIdx.x < nb) ? bsums[threadIdx.x] : 0;
    int lane = threadIdx.x & 63, wid = threadIdx.x >> 6;
    int incl = v;
    #pragma unroll
    for (int off = 1; off < 64; off <<= 1) {
        int t = __shfl_up(incl, off, 64);
        if (lane >= off) incl += t;
    }
    if (lane == 63) wsum[wid] = incl;
    __syncthreads();
    int wprefix = 0;
    #pragma unroll
    for (int w = 0; w < 4; ++w)
        if (w < wid) wprefix += wsum[w];
    if ((int)threadIdx.x < nb) bsums[threadIdx.x] = wprefix + incl - v;
    if (threadIdx.x == 255) *total = wprefix + incl;
}

// ---------------------------------------------------------------- bucketed CSR build
__global__ void bucket_count_k(const int* __restrict__ dst, int* __restrict__ bcnt, int E) {
    __shared__ int cnt[NBUK];
    int tid = threadIdx.x;
    for (int i = tid; i < NBUK; i += 256) cnt[i] = 0;
    __syncthreads();
    int e0 = blockIdx.x * CHUNK;
    int eend = min(e0 + CHUNK, E);
    for (int e = e0 + tid; e < eend; e += 256)
        atomicAdd(&cnt[dst[e] >> 8], 1);
    __syncthreads();
    for (int i = tid; i < NBUK; i += 256)
        if (cnt[i]) atomicAdd(&bcnt[i], cnt[i]);
}

__global__ void bin_scatter_k(const int* __restrict__ src, const int* __restrict__ dst,
                              const int* __restrict__ bbase, int* __restrict__ bcur,
                              uint2* __restrict__ staging, int E) {
    __shared__ int cnt[NBUK];
    __shared__ int gbase[NBUK];
    int tid = threadIdx.x;
    for (int i = tid; i < NBUK; i += 256) cnt[i] = 0;
    __syncthreads();
    int e0 = blockIdx.x * CHUNK;
    int eend = min(e0 + CHUNK, E);
    for (int e = e0 + tid; e < eend; e += 256)
        atomicAdd(&cnt[dst[e] >> 8], 1);
    __syncthreads();
    for (int i = tid; i < NBUK; i += 256) {
        int c = cnt[i];
        gbase[i] = c ? (bbase[i] + atomicAdd(&bcur[i], c)) : 0;
        cnt[i] = 0;  // reuse as local cursor
    }
    __syncthreads();
    for (int e = e0 + tid; e < eend; e += 256) {
        int d = dst[e];
        int b = d >> 8;
        int l = atomicAdd(&cnt[b], 1);
        uint2 p; p.x = (unsigned)src[e]; p.y = (unsigned)d;
        staging[(size_t)gbase[b] + l] = p;
    }
}

__global__ void csr_build_k(const uint2* __restrict__ staging, const int* __restrict__ bbase,
                            int* __restrict__ row_ofs, int* __restrict__ csr) {
    __shared__ int ldeg[256];
    __shared__ int lofs[256];
    __shared__ int wsum[4];
    int b = blockIdx.x, tid = threadIdx.x;
    int base = bbase[b];
    int cnt = bbase[b + 1] - base;
    ldeg[tid] = 0;
    __syncthreads();
    const uint2* sp = staging + base;
    for (int i = tid; i < cnt; i += 256)
        atomicAdd(&ldeg[sp[i].y & 255], 1);
    __syncthreads();
    int v = ldeg[tid];
    int lane = tid & 63, wid = tid >> 6;
    int incl = v;
    #pragma unroll
    for (int off = 1; off < 64; off <<= 1) {
        int t = __shfl_up(incl, off, 64);
        if (lane >= off) incl += t;
    }
    if (lane == 63) wsum[wid] = incl;
    __syncthreads();
    int wprefix = 0;
    #pragma unroll
    for (int w = 0; w < 4; ++w)
        if (w < wid) wprefix += wsum[w];
    int excl = wprefix + incl - v;
    lofs[tid] = excl;
    int node = b * 256 + tid;
    if (node < N_NODES) row_ofs[node] = base + excl;
    if (b == NBUK - 1 && tid == 0) row_ofs[N_NODES] = N_EDGES;
    ldeg[tid] = 0;  // reuse as cursor
    __syncthreads();
    for (int i = tid; i < cnt; i += 256) {
        uint2 p = sp[i];
        int d = (int)p.y & 255;
        int pos = atomicAdd(&ldeg[d], 1);
        csr[base + lofs[d] + pos] = (int)p.x;
    }
}

// gofs[g] = lower_bound(batch, g)  (batch sorted); gofs[G] = n
__global__ void gofs_search_k(const int* __restrict__ batch, int* __restrict__ gofs,
                              int n, int G) {
    int g = blockIdx.x * blockDim.x + threadIdx.x;
    if (g > G) return;
    if (g == G) { gofs[G] = n; return; }
    int lo = 0, hi = n;
    while (lo < hi) {
        int mid = (lo + hi) >> 1;
        if (batch[mid] < g) lo = mid + 1; else hi = mid;
    }
    gofs[g] = lo;
}

// ---------------------------------------------------------------- converts
__global__ void wt_concat_k(const float* __restrict__ Wl, const float* __restrict__ Wr,
                            unsigned short* __restrict__ out, int K1, int K2, int N) {
    int idx = blockIdx.x * blockDim.x + threadIdx.x;
    int KT = K1 + K2;
    if (idx >= N * KT) return;
    int n = idx / KT, k = idx % KT;
    float v = (k < K1) ? Wl[(size_t)k * N + n] : Wr[(size_t)(k - K1) * N + n];
    out[idx] = f2b(v);
}

// fp32 -> (bf16, fp8) in one pass. Thread handles 8 floats.
__global__ void f2b8_k(const float* __restrict__ in, unsigned short* __restrict__ outb,
                       unsigned char* __restrict__ out8, size_t n8) {
    size_t i = (size_t)blockIdx.x * blockDim.x + threadIdx.x;
    if (i >= n8) return;
    float4 a = ((const float4*)in)[i * 2];
    float4 b = ((const float4*)in)[i * 2 + 1];
    unsigned short ob[8];
    ob[0] = f2b(a.x); ob[1] = f2b(a.y); ob[2] = f2b(a.z); ob[3] = f2b(a.w);
    ob[4] = f2b(b.x); ob[5] = f2b(b.y); ob[6] = f2b(b.z); ob[7] = f2b(b.w);
    ((uint4*)outb)[i] = *(const uint4*)ob;
    int w0 = 0, w1 = 0;
    w0 = __builtin_amdgcn_cvt_pk_fp8_f32(a.x, a.y, w0, false);
    w0 = __builtin_amdgcn_cvt_pk_fp8_f32(a.z, a.w, w0, true);
    w1 = __builtin_amdgcn_cvt_pk_fp8_f32(b.x, b.y, w1, false);
    w1 = __builtin_amdgcn_cvt_pk_fp8_f32(b.z, b.w, w1, true);
    uint2 o8; o8.x = (unsigned int)w0; o8.y = (unsigned int)w1;
    ((uint2*)out8)[i] = o8;
}

// bf16 -> fp8 e4m3 (HW cvt). Each thread: 16 bf16 in (32B) -> 16 fp8 out (16B).
__global__ void b2f8_k(const unsigned short* __restrict__ in, unsigned char* __restrict__ out,
                       size_t n16) {
    size_t i = (size_t)blockIdx.x * blockDim.x + threadIdx.x;
    if (i >= n16) return;
    uint4 v0 = ((const uint4*)in)[i * 2];
    uint4 v1 = ((const uint4*)in)[i * 2 + 1];
    const unsigned int* q = (const unsigned int*)&v0;
    const unsigned int* r = (const unsigned int*)&v1;
    uint4 o;
    unsigned int* po = (unsigned int*)&o;
    #pragma unroll
    for (int t = 0; t < 2; ++t) {
        int w = 0;
        w = __builtin_amdgcn_cvt_pk_fp8_f32(b2f((unsigned short)(q[t * 2] & 0xFFFF)),
                                            b2f((unsigned short)(q[t * 2] >> 16)), w, false);
        w = __builtin_amdgcn_cvt_pk_fp8_f32(b2f((unsigned short)(q[t * 2 + 1] & 0xFFFF)),
                                            b2f((unsigned short)(q[t * 2 + 1] >> 16)), w, true);
        po[t] = (unsigned int)w;
    }
    #pragma unroll
    for (int t = 0; t < 2; ++t) {
        int w = 0;
        w = __builtin_amdgcn_cvt_pk_fp8_f32(b2f((unsigned short)(r[t * 2] & 0xFFFF)),
                                            b2f((unsigned short)(r[t * 2] >> 16)), w, false);
        w = __builtin_amdgcn_cvt_pk_fp8_f32(b2f((unsigned short)(r[t * 2 + 1] & 0xFFFF)),
                                            b2f((unsigned short)(r[t * 2 + 1] >> 16)), w, true);
        po[2 + t] = (unsigned int)w;
    }
    ((uint4*)out)[i] = o;
}

// ---------------------------------------------------------------- mean aggregation
// fp8 in [n,C] -> bf16 mean out [n,C]. One wave per node; GL=C/16 lanes x 16B per
// gather, NG=64/GL edge-groups, 2x unroll. Cross-group shfl_xor reduce.
template <int C>
__global__ void agg_f8_k(const unsigned char* __restrict__ X8, const int* __restrict__ row_ofs,
                         const int* __restrict__ csr, unsigned short* __restrict__ out, int n) {
    constexpr int GL = C / 16;
    constexpr int NG = 64 / GL;
    int w = (int)((blockIdx.x * blockDim.x + threadIdx.x) >> 6);
    int lane = threadIdx.x & 63;
    if (w >= n) return;
    int g = lane / GL, il = lane % GL;
    int s = row_ofs[w], e = row_ofs[w + 1];
    float a[16];
    #pragma unroll
    for (int t = 0; t < 16; ++t) a[t] = 0.f;

    int j = s + g;
    for (; j + NG < e; j += 2 * NG) {
        int i0 = csr[j], i1 = csr[j + NG];
        uint4 r0 = *(const uint4*)&X8[(size_t)i0 * C + il * 16];
        uint4 r1 = *(const uint4*)&X8[(size_t)i1 * C + il * 16];
        const unsigned int* q0 = (const unsigned int*)&r0;
        const unsigned int* q1 = (const unsigned int*)&r1;
        #pragma unroll
        for (int t = 0; t < 4; ++t) {
            f32x2 lo = __builtin_amdgcn_cvt_pk_f32_fp8(q0[t], false);
            f32x2 hi = __builtin_amdgcn_cvt_pk_f32_fp8(q0[t], true);
            a[t * 4 + 0] += lo.x; a[t * 4 + 1] += lo.y;
            a[t * 4 + 2] += hi.x; a[t * 4 + 3] += hi.y;
        }
        #pragma unroll
        for (int t = 0; t < 4; ++t) {
            f32x2 lo = __builtin_amdgcn_cvt_pk_f32_fp8(q1[t], false);
            f32x2 hi = __builtin_amdgcn_cvt_pk_f32_fp8(q1[t], true);
            a[t * 4 + 0] += lo.x; a[t * 4 + 1] += lo.y;
            a[t * 4 + 2] += hi.x; a[t * 4 + 3] += hi.y;
        }
    }
    if (j < e) {
        int i0 = csr[j];
        uint4 r0 = *(const uint4*)&X8[(size_t)i0 * C + il * 16];
        const unsigned int* q0 = (const unsigned int*)&r0;
        #pragma unroll
        for (int t = 0; t < 4; ++t) {
            f32x2 lo = __builtin_amdgcn_cvt_pk_f32_fp8(q0[t], false);
            f32x2 hi = __builtin_amdgcn_cvt_pk_f32_fp8(q0[t], true);
            a[t * 4 + 0] += lo.x; a[t * 4 + 1] += lo.y;
            a[t * 4 + 2] += hi.x; a[t * 4 + 3] += hi.y;
        }
    }

    #pragma unroll
    for (int m = GL; m < 64; m <<= 1)
        #pragma unroll
        for (int t = 0; t < 16; ++t) a[t] += __shfl_xor(a[t], m, 64);

    if (g == 0) {
        float inv = 1.0f / (float)max(e - s, 1);
        uint4 o0, o1;
        unsigned short* p0 = (unsigned short*)&o0;
        unsigned short* p1 = (unsigned short*)&o1;
        #pragma unroll
        for (int t = 0; t < 8; ++t) p0[t] = f2b(a[t] * inv);
        #pragma unroll
        for (int t = 0; t < 8; ++t) p1[t] = f2b(a[8 + t] * inv);
        *(uint4*)&out[(size_t)w * C + il * 16] = o0;
        *(uint4*)&out[(size_t)w * C + il * 16 + 8] = o1;
    }
}

// pool: bf16 input [N,256] -> fp32 pooled [G,256]; one wave per graph
__global__ void pool_mean_k(const unsigned short* __restrict__ H, const int* __restrict__ gofs,
                            float* __restrict__ pooled, int G) {
    int g = (int)((blockIdx.x * blockDim.x + threadIdx.x) >> 6);
    int lane = threadIdx.x & 63;
    if (g >= G) return;
    int s = gofs[g], e = gofs[g + 1];
    float a0 = 0.f, a1 = 0.f, a2 = 0.f, a3 = 0.f;
    for (int r = s; r < e; ++r) {
        ushort4 t = ((const ushort4*)(H + (size_t)r * HID))[lane];
        a0 += b2f(t.x); a1 += b2f(t.y); a2 += b2f(t.z); a3 += b2f(t.w);
    }
    float inv = 1.0f / (float)max(e - s, 1);
    float4 o; o.x = a0 * inv; o.y = a1 * inv; o.z = a2 * inv; o.w = a3 * inv;
    ((float4*)(pooled + (size_t)g * HID))[lane] = o;
}

// ---------------------------------------------------------------- bf16 MFMA GEMM
// 128x128 tile, 4 waves 2x2, each wave 4x4 frags of 16x16x32, BK=32.
// Double-buffered LDS; global_load_lds prefetch held across raw barriers.
// Lane mapping per wave: row = lane&15, chunk = lane>>4 -> global reads are
// 16 rows x 64B contiguous lines (good coalescing) AND the forced LDS layout
// (base + lane*16B) becomes chunk-major: frag reads are 1024B contiguous
// across the wave -> zero bank conflicts (both R9's and R10's good halves).
__launch_bounds__(256)
__global__ void mfma_gemm_k(const unsigned short* __restrict__ A1, int K1,
                            const unsigned short* __restrict__ A2, int K2,
                            const unsigned short* __restrict__ Bt,
                            const float* __restrict__ bias, int M, int Nfull,
                            void* __restrict__ Cptr, int c_bf16, int do_relu) {
    __shared__ short ldsA[2 * 4096];
    __shared__ short ldsB[2 * 4096];
    int tid = threadIdx.x, lane = tid & 63;
    int wid = tid >> 6, wm = wid >> 1, wn = wid & 1;
    int row0 = blockIdx.x * 128, col0 = blockIdx.y * 128;
    int q = lane >> 4, l15 = lane & 15;
    int KT = K1 + K2;
    int nk = KT / 32;

    // wave `wid` stages rows wid*16 + l15 of each 64-row half, chunk = q.
    // LDS short addr (HW): h*2048 + wid*512 + lane*8 = h*2048+wid*512+q*128+l15*8
    // -> holds A[h*64 + wid*16 + l15][kt + q*8 ..+7].  Frag read for row
    // wm*64 + i*16 + l15, chunk q: offset wm*2048 + i*512 + q*128 + l15*8.
    auto stage = [&](int t) {
        int kt = t * 32;
        const unsigned short* Asrc; int kk, Ks;
        if (kt < K1) { Asrc = A1; kk = kt; Ks = K1; }
        else         { Asrc = A2; kk = kt - K1; Ks = K2; }
        short* bA = ldsA + (t & 1) * 4096;
        short* bB = ldsB + (t & 1) * 4096;
        int rloc = wid * 16 + l15;
        int koff = q * 8;
        #pragma unroll
        for (int h = 0; h < 2; ++h) {
            int r = h * 64 + rloc;
            int gr = min(row0 + r, M - 1);
            GLOAD_LDS16(Asrc + (size_t)gr * Ks + kk + koff, bA + h * 2048 + wid * 512);
            GLOAD_LDS16(Bt + (size_t)(col0 + r) * KT + kt + koff, bB + h * 2048 + wid * 512);
        }
    };

    f32x4 acc[4][4] = {};

    stage(0);
    stage(1);

    for (int t = 0; t < nk; ++t) {
        if (t == nk - 1) asm volatile("s_waitcnt vmcnt(0)" ::: "memory");
        else             asm volatile("s_waitcnt vmcnt(4)" ::: "memory");
        asm volatile("s_barrier" ::: "memory");   // tile t visible to all waves

        const short* bA = ldsA + (t & 1) * 4096;
        const short* bB = ldsB + (t & 1) * 4096;
        bf16x8 af[4], bfr[4];
        #pragma unroll
        for (int i = 0; i < 4; ++i)
            af[i] = *(const bf16x8*)&bA[wm * 2048 + i * 512 + q * 128 + l15 * 8];
        #pragma unroll
        for (int j = 0; j < 4; ++j)
            bfr[j] = *(const bf16x8*)&bB[wn * 2048 + j * 512 + q * 128 + l15 * 8];
        #pragma unroll
        for (int i = 0; i < 4; ++i)
            #pragma unroll
            for (int j = 0; j < 4; ++j)
                acc[i][j] = __builtin_amdgcn_mfma_f32_16x16x32_bf16(af[i], bfr[j], acc[i][j], 0, 0, 0);

        asm volatile("s_barrier" ::: "memory");   // all waves done reading buf
        if (t + 2 < nk) stage(t + 2);             // refill the buffer just consumed
    }

    // epilogue: D layout col=lane&15, row=quad*4+reg
    #pragma unroll
    for (int i = 0; i < 4; ++i) {
        #pragma unroll
        for (int reg = 0; reg < 4; ++reg) {
            int r = row0 + wm * 64 + i * 16 + q * 4 + reg;
            if (r < M) {
                #pragma unroll
                for (int j = 0; j < 4; ++j) {
                    int cc = col0 + wn * 64 + j * 16 + l15;
                    float v = acc[i][j][reg] + bias[cc];
                    if (do_relu) v = fmaxf(v, 0.f);
                    if (c_bf16) ((unsigned short*)Cptr)[(size_t)r * Nfull + cc] = f2b(v);
                    else        ((float*)Cptr)[(size_t)r * Nfull + cc] = v;
                }
            }
        }
    }
}

// ---------------------------------------------------------------- fp32 GEMM (head only)
#define BM_ 64
#define BK_ 16

template <int BN_>
__launch_bounds__(256)
__global__ void gemm2_k(const float* __restrict__ A1, const float* __restrict__ B1, int K1,
                        const float* __restrict__ bias, float* __restrict__ C,
                        int M, int N, int do_relu) {
    constexpr int TCOLS = BN_ / 8;
    constexpr int TROWS = 256 / TCOLS;
    constexpr int TM = BM_ / TROWS;
    __shared__ float As[BK_][BM_ + 4];
    __shared__ float Bs[BK_][BN_ + 4];
    int tid = threadIdx.x;
    int row0 = blockIdx.x * BM_;
    int col0 = blockIdx.y * BN_;
    int tx = tid % TCOLS, ty = tid / TCOLS;

    float acc[TM][8];
    #pragma unroll
    for (int i = 0; i < TM; ++i)
        #pragma unroll
        for (int j = 0; j < 8; ++j) acc[i][j] = 0.f;

    int ar = tid >> 2;
    int ak = (tid & 3) * 4;

    for (int kt = 0; kt < K1; kt += BK_) {
        {
            int r = row0 + ar;
            int rc = min(r, M - 1);
            float4 v = *(const float4*)(A1 + (size_t)rc * K1 + kt + ak);
            As[ak + 0][ar] = v.x;
            As[ak + 1][ar] = v.y;
            As[ak + 2][ar] = v.z;
            As[ak + 3][ar] = v.w;
        }
        {
            #pragma unroll
            for (int h = 0; h < BN_ / 64; ++h) {
                int idx = h * 256 + tid;
                int kr = idx / (BN_ / 4);
                int c4 = idx % (BN_ / 4);
                float4 v = *(const float4*)(B1 + (size_t)(kt + kr) * N + col0 + c4 * 4);
                *(float4*)&Bs[kr][c4 * 4] = v;
            }
        }
        __syncthreads();

        #pragma unroll
        for (int k = 0; k < BK_; ++k) {
            float a[TM], b[8];
            #pragma unroll
            for (int v = 0; v < TM / 4; ++v)
                *(float4*)&a[v * 4] = *(const float4*)&As[k][ty * TM + v * 4];
            *(float4*)&b[0] = *(const float4*)&Bs[k][tx * 8];
            *(float4*)&b[4] = *(const float4*)&Bs[k][tx * 8 + 4];
            #pragma unroll
            for (int i = 0; i < TM; ++i)
                #pragma unroll
                for (int j = 0; j < 8; ++j) acc[i][j] = fmaf(a[i], b[j], acc[i][j]);
        }
        __syncthreads();
    }

    float bv[8];
    #pragma unroll
    for (int j = 0; j < 8; ++j) bv[j] = bias[col0 + tx * 8 + j];
    #pragma unroll
    for (int i = 0; i < TM; ++i) {
        int r = row0 + ty * TM + i;
        if (r < M) {
            float* cp = C + (size_t)r * N + col0 + tx * 8;
            float o[8];
            #pragma unroll
            for (int j = 0; j < 8; ++j) {
                float v = acc[i][j] + bv[j];
                o[j] = do_relu ? fmaxf(v, 0.f) : v;
            }
            *(float4*)(cp + 0) = *(float4*)&o[0];
            *(float4*)(cp + 4) = *(float4*)&o[4];
        }
    }
}

// ---------------------------------------------------------------- launcher
extern "C" void kernel_launch(void* const* d_in, const int* in_sizes, int n_in,
                              void* d_out, int out_size, void* d_ws, size_t ws_size,
                              hipStream_t stream) {
    const float* x    = (const float*)d_in[0];
    const int*   ei   = (const int*)d_in[1];
    const int*   batch= (const int*)d_in[2];
    const float* W1l  = (const float*)d_in[3];
    const float* b1   = (const float*)d_in[4];
    const float* W1r  = (const float*)d_in[5];
    const float* W2l  = (const float*)d_in[6];
    const float* b2   = (const float*)d_in[7];
    const float* W2r  = (const float*)d_in[8];
    const float* W3   = (const float*)d_in[9];
    const float* b3   = (const float*)d_in[10];
    const float* W4   = (const float*)d_in[11];
    const float* b4   = (const float*)d_in[12];
    float* out = (float*)d_out;

    const int N = N_NODES, E = N_EDGES, G = N_GRAPHS;
    const int* src = ei;
    const int* dst = ei + E;

    char* ws = (char*)d_ws;
    size_t off = 0;
    auto alloc = [&](size_t bytes) -> char* {
        off = (off + 255) & ~(size_t)255;
        char* p = ws + off;
        off += bytes;
        return p;
    };
    int* bcnt    = (int*)alloc((size_t)NBUK * 4);
    int* bcur    = (int*)alloc((size_t)NBUK * 4);
    size_t zero_span = (size_t)((char*)(bcur + NBUK) - (char*)bcnt);
    int* bbase   = (int*)alloc((size_t)(NBUK + 1) * 4);
    int* bsums   = (int*)alloc(256 * 4);
    int* row_ofs = (int*)alloc((size_t)(N + 1) * 4);
    int* gofs    = (int*)alloc((size_t)(G + 1) * 4);
    uint2* staging = (uint2*)alloc((size_t)E * 8);
    int* csr     = (int*)alloc((size_t)E * 4);
    unsigned short* xb    = (unsigned short*)alloc((size_t)N * IN_CH * 2);
    unsigned short* mean1 = (unsigned short*)alloc((size_t)N * IN_CH * 2);
    unsigned short* h1    = (unsigned short*)alloc((size_t)N * HID * 2);
    unsigned short* mean2 = (unsigned short*)alloc((size_t)N * HID * 2);
    unsigned short* h2    = xb;  // xb+mean1 contiguous span reused for h2 [N,256]
    unsigned char*  x8    = (unsigned char*)alloc((size_t)N * IN_CH);
    unsigned char*  h1f8  = (unsigned char*)alloc((size_t)N * HID);
    unsigned short* W1T   = (unsigned short*)alloc((size_t)HID * (IN_CH + IN_CH) * 2);
    unsigned short* W2T   = (unsigned short*)alloc((size_t)HID * (HID + HID) * 2);
    float* pooled = (float*)alloc((size_t)G * HID * 4);
    float* hidden = (float*)alloc((size_t)G * HID * 4);
    (void)ws_size;

    hipMemsetAsync(bcnt, 0, zero_span, stream);

    const int EB = (E + CHUNK - 1) / CHUNK;  // 196
    bucket_count_k<<<EB, 256, 0, stream>>>(dst, bcnt, E);
    scan1_k<<<1, 256, 0, stream>>>(bcnt, bbase, bsums, NBUK);
    scan2_k<<<1, 256, 0, stream>>>(bsums, 1, bbase + NBUK);
    bin_scatter_k<<<EB, 256, 0, stream>>>(src, dst, bbase, bcur, staging, E);
    csr_build_k<<<NBUK, 256, 0, stream>>>(staging, bbase, row_ofs, csr);

    gofs_search_k<<<(G + 256) / 256, 256, 0, stream>>>(batch, gofs, N, G);

    wt_concat_k<<<(HID * 2 * IN_CH + 255) / 256, 256, 0, stream>>>(W1l, W1r, W1T, IN_CH, IN_CH, HID);
    wt_concat_k<<<(HID * 2 * HID + 255) / 256, 256, 0, stream>>>(W2l, W2r, W2T, HID, HID, HID);
    f2b8_k<<<(int)(((size_t)N * IN_CH / 8 + 255) / 256), 256, 0, stream>>>(
        x, xb, x8, (size_t)N * IN_CH / 8);

    const int MB = (N + 127) / 128;

    // layer 1: mean1 = mean-agg(x8) [fp8 gather]; h1 = relu([mean1|xb] @ W1T^T + b1)
    agg_f8_k<IN_CH><<<(N + 3) / 4, 256, 0, stream>>>(x8, row_ofs, csr, mean1, N);
    mfma_gemm_k<<<dim3(MB, HID / 128), 256, 0, stream>>>(
        mean1, IN_CH, xb, IN_CH, W1T, b1, N, HID, h1, 1, 1);

    // fp8 mirror of h1 for the layer-2 gather
    b2f8_k<<<(int)(((size_t)N * HID / 16 + 255) / 256), 256, 0, stream>>>(
        h1, h1f8, (size_t)N * HID / 16);

    // layer 2: mean2 = mean-agg(h1f8) [fp8 gather]; h2 = relu([mean2|h1] @ W2T^T + b2)
    agg_f8_k<HID><<<(N + 3) / 4, 256, 0, stream>>>(h1f8, row_ofs, csr, mean2, N);
    mfma_gemm_k<<<dim3(MB, HID / 128), 256, 0, stream>>>(
        mean2, HID, h1, HID, W2T, b2, N, HID, h2, 1, 1);

    // global mean pool (bf16 in, fp32 out)
    pool_mean_k<<<(G + 3) / 4, 256, 0, stream>>>(h2, gofs, pooled, G);

    // MLP head (fp32)
    gemm2_k<HID><<<dim3(G / BM_, 1), 256, 0, stream>>>(
        pooled, W3, HID, b3, hidden, G, HID, 1);
    gemm2_k<OUT_CH><<<dim3(G / BM_, 1), 256, 0, stream>>>(
        hidden, W4, HID, b4, out, G, OUT_CH, 0);
}

// Round 12
// 554.886 us; speedup vs baseline: 1.0619x; 1.0547x over previous
//
#include <hip/hip_runtime.h>

#define N_NODES 100000
#define N_EDGES 1600000
#define IN_CH 128
#define HID 256
#define OUT_CH 128
#define N_GRAPHS 2048

#define NBUK 391          // ceil(N_NODES / 256)
#define CHUNK 8192        // edges per binning block

typedef __attribute__((ext_vector_type(8))) short bf16x8;
typedef __attribute__((ext_vector_type(4))) float f32x4;
typedef __attribute__((ext_vector_type(2))) float f32x2;

__device__ inline unsigned short f2b(float f) {  // RNE fp32 -> bf16
    unsigned int u = __builtin_bit_cast(unsigned int, f);
    u = (u + 0x7FFF + ((u >> 16) & 1)) >> 16;
    return (unsigned short)u;
}
__device__ inline float b2f(unsigned short h) {
    unsigned int u = (unsigned int)h << 16;
    return __builtin_bit_cast(float, u);
}

// async global->LDS, 16 B per lane; dst is wave-uniform base, HW adds lane*16
#define GLOAD_LDS16(gsrc, ldst)                                                   \
    __builtin_amdgcn_global_load_lds(                                             \
        (const __attribute__((address_space(1))) void*)(gsrc),                    \
        (__attribute__((address_space(3))) void*)(ldst), 16, 0, 0)

// ---------------------------------------------------------------- scans (for bucket counts)
#define SCAN_ITEMS 8
#define SCAN_TILE (256 * SCAN_ITEMS)

__global__ void scan1_k(const int* __restrict__ in, int* __restrict__ out,
                        int* __restrict__ bsums, int n) {
    __shared__ int wsum[4];
    int base = blockIdx.x * SCAN_TILE + (int)threadIdx.x * SCAN_ITEMS;
    int v[SCAN_ITEMS];
    int s = 0;
    #pragma unroll
    for (int i = 0; i < SCAN_ITEMS; ++i) {
        v[i] = (base + i < n) ? in[base + i] : 0;
        s += v[i];
    }
    int lane = threadIdx.x & 63, wid = threadIdx.x >> 6;
    int incl = s;
    #pragma unroll
    for (int off = 1; off < 64; off <<= 1) {
        int t = __shfl_up(incl, off, 64);
        if (lane >= off) incl += t;
    }
    if (lane == 63) wsum[wid] = incl;
    __syncthreads();
    int wprefix = 0;
    #pragma unroll
    for (int w = 0; w < 4; ++w)
        if (w < wid) wprefix += wsum[w];
    int run = wprefix + incl - s;
    #pragma unroll
    for (int i = 0; i < SCAN_ITEMS; ++i) {
        if (base + i < n) out[base + i] = run;
        run += v[i];
    }
    if (threadIdx.x == 255) bsums[blockIdx.x] = wprefix + incl;
}

__global__ void scan2_k(int* __restrict__ bsums, int nb, int* __restrict__ total) {
    __shared__ int wsum[4];
    int v = ((int)threadIdx.x < nb) ? bsums[threadIdx.x] : 0;
    int lane = threadIdx.x & 63, wid = threadIdx.x >> 6;
    int incl = v;
    #pragma unroll
    for (int off = 1; off < 64; off <<= 1) {
        int t = __shfl_up(incl, off, 64);
        if (lane >= off) incl += t;
    }
    if (lane == 63) wsum[wid] = incl;
    __syncthreads();
    int wprefix = 0;
    #pragma unroll
    for (int w = 0; w < 4; ++w)
        if (w < wid) wprefix += wsum[w];
    if ((int)threadIdx.x < nb) bsums[threadIdx.x] = wprefix + incl - v;
    if (threadIdx.x == 255) *total = wprefix + incl;
}

// ---------------------------------------------------------------- bucketed CSR build
__global__ void bucket_count_k(const int* __restrict__ dst, int* __restrict__ bcnt, int E) {
    __shared__ int cnt[NBUK];
    int tid = threadIdx.x;
    for (int i = tid; i < NBUK; i += 256) cnt[i] = 0;
    __syncthreads();
    int e0 = blockIdx.x * CHUNK;
    int eend = min(e0 + CHUNK, E);
    for (int e = e0 + tid; e < eend; e += 256)
        atomicAdd(&cnt[dst[e] >> 8], 1);
    __syncthreads();
    for (int i = tid; i < NBUK; i += 256)
        if (cnt[i]) atomicAdd(&bcnt[i], cnt[i]);
}

__global__ void bin_scatter_k(const int* __restrict__ src, const int* __restrict__ dst,
                              const int* __restrict__ bbase, int* __restrict__ bcur,
                              uint2* __restrict__ staging, int E) {
    __shared__ int cnt[NBUK];
    __shared__ int gbase[NBUK];
    int tid = threadIdx.x;
    for (int i = tid; i < NBUK; i += 256) cnt[i] = 0;
    __syncthreads();
    int e0 = blockIdx.x * CHUNK;
    int eend = min(e0 + CHUNK, E);
    for (int e = e0 + tid; e < eend; e += 256)
        atomicAdd(&cnt[dst[e] >> 8], 1);
    __syncthreads();
    for (int i = tid; i < NBUK; i += 256) {
        int c = cnt[i];
        gbase[i] = c ? (bbase[i] + atomicAdd(&bcur[i], c)) : 0;
        cnt[i] = 0;  // reuse as local cursor
    }
    __syncthreads();
    for (int e = e0 + tid; e < eend; e += 256) {
        int d = dst[e];
        int b = d >> 8;
        int l = atomicAdd(&cnt[b], 1);
        uint2 p; p.x = (unsigned)src[e]; p.y = (unsigned)d;
        staging[(size_t)gbase[b] + l] = p;
    }
}

__global__ void csr_build_k(const uint2* __restrict__ staging, const int* __restrict__ bbase,
                            int* __restrict__ row_ofs, int* __restrict__ csr) {
    __shared__ int ldeg[256];
    __shared__ int lofs[256];
    __shared__ int wsum[4];
    int b = blockIdx.x, tid = threadIdx.x;
    int base = bbase[b];
    int cnt = bbase[b + 1] - base;
    ldeg[tid] = 0;
    __syncthreads();
    const uint2* sp = staging + base;
    for (int i = tid; i < cnt; i += 256)
        atomicAdd(&ldeg[sp[i].y & 255], 1);
    __syncthreads();
    int v = ldeg[tid];
    int lane = tid & 63, wid = tid >> 6;
    int incl = v;
    #pragma unroll
    for (int off = 1; off < 64; off <<= 1) {
        int t = __shfl_up(incl, off, 64);
        if (lane >= off) incl += t;
    }
    if (lane == 63) wsum[wid] = incl;
    __syncthreads();
    int wprefix = 0;
    #pragma unroll
    for (int w = 0; w < 4; ++w)
        if (w < wid) wprefix += wsum[w];
    int excl = wprefix + incl - v;
    lofs[tid] = excl;
    int node = b * 256 + tid;
    if (node < N_NODES) row_ofs[node] = base + excl;
    if (b == NBUK - 1 && tid == 0) row_ofs[N_NODES] = N_EDGES;
    ldeg[tid] = 0;  // reuse as cursor
    __syncthreads();
    for (int i = tid; i < cnt; i += 256) {
        uint2 p = sp[i];
        int d = (int)p.y & 255;
        int pos = atomicAdd(&ldeg[d], 1);
        csr[base + lofs[d] + pos] = (int)p.x;
    }
}

// gofs[g] = lower_bound(batch, g)  (batch sorted); gofs[G] = n
__global__ void gofs_search_k(const int* __restrict__ batch, int* __restrict__ gofs,
                              int n, int G) {
    int g = blockIdx.x * blockDim.x + threadIdx.x;
    if (g > G) return;
    if (g == G) { gofs[G] = n; return; }
    int lo = 0, hi = n;
    while (lo < hi) {
        int mid = (lo + hi) >> 1;
        if (batch[mid] < g) lo = mid + 1; else hi = mid;
    }
    gofs[g] = lo;
}

// ---------------------------------------------------------------- converts
__global__ void wt_concat_k(const float* __restrict__ Wl, const float* __restrict__ Wr,
                            unsigned short* __restrict__ out, int K1, int K2, int N) {
    int idx = blockIdx.x * blockDim.x + threadIdx.x;
    int KT = K1 + K2;
    if (idx >= N * KT) return;
    int n = idx / KT, k = idx % KT;
    float v = (k < K1) ? Wl[(size_t)k * N + n] : Wr[(size_t)(k - K1) * N + n];
    out[idx] = f2b(v);
}

// fp32 -> (bf16, fp8) in one pass. Thread handles 8 floats.
__global__ void f2b8_k(const float* __restrict__ in, unsigned short* __restrict__ outb,
                       unsigned char* __restrict__ out8, size_t n8) {
    size_t i = (size_t)blockIdx.x * blockDim.x + threadIdx.x;
    if (i >= n8) return;
    float4 a = ((const float4*)in)[i * 2];
    float4 b = ((const float4*)in)[i * 2 + 1];
    unsigned short ob[8];
    ob[0] = f2b(a.x); ob[1] = f2b(a.y); ob[2] = f2b(a.z); ob[3] = f2b(a.w);
    ob[4] = f2b(b.x); ob[5] = f2b(b.y); ob[6] = f2b(b.z); ob[7] = f2b(b.w);
    ((uint4*)outb)[i] = *(const uint4*)ob;
    int w0 = 0, w1 = 0;
    w0 = __builtin_amdgcn_cvt_pk_fp8_f32(a.x, a.y, w0, false);
    w0 = __builtin_amdgcn_cvt_pk_fp8_f32(a.z, a.w, w0, true);
    w1 = __builtin_amdgcn_cvt_pk_fp8_f32(b.x, b.y, w1, false);
    w1 = __builtin_amdgcn_cvt_pk_fp8_f32(b.z, b.w, w1, true);
    uint2 o8; o8.x = (unsigned int)w0; o8.y = (unsigned int)w1;
    ((uint2*)out8)[i] = o8;
}

// ---------------------------------------------------------------- mean aggregation
// fp8 in [n,C] -> bf16 mean out [n,C]. One wave per node; GL=C/16 lanes x 16B per
// gather, NG=64/GL edge-groups, 2x unroll. Cross-group shfl_xor reduce.
template <int C>
__global__ void agg_f8_k(const unsigned char* __restrict__ X8, const int* __restrict__ row_ofs,
                         const int* __restrict__ csr, unsigned short* __restrict__ out, int n) {
    constexpr int GL = C / 16;
    constexpr int NG = 64 / GL;
    int w = (int)((blockIdx.x * blockDim.x + threadIdx.x) >> 6);
    int lane = threadIdx.x & 63;
    if (w >= n) return;
    int g = lane / GL, il = lane % GL;
    int s = row_ofs[w], e = row_ofs[w + 1];
    float a[16];
    #pragma unroll
    for (int t = 0; t < 16; ++t) a[t] = 0.f;

    int j = s + g;
    for (; j + NG < e; j += 2 * NG) {
        int i0 = csr[j], i1 = csr[j + NG];
        uint4 r0 = *(const uint4*)&X8[(size_t)i0 * C + il * 16];
        uint4 r1 = *(const uint4*)&X8[(size_t)i1 * C + il * 16];
        const unsigned int* q0 = (const unsigned int*)&r0;
        const unsigned int* q1 = (const unsigned int*)&r1;
        #pragma unroll
        for (int t = 0; t < 4; ++t) {
            f32x2 lo = __builtin_amdgcn_cvt_pk_f32_fp8(q0[t], false);
            f32x2 hi = __builtin_amdgcn_cvt_pk_f32_fp8(q0[t], true);
            a[t * 4 + 0] += lo.x; a[t * 4 + 1] += lo.y;
            a[t * 4 + 2] += hi.x; a[t * 4 + 3] += hi.y;
        }
        #pragma unroll
        for (int t = 0; t < 4; ++t) {
            f32x2 lo = __builtin_amdgcn_cvt_pk_f32_fp8(q1[t], false);
            f32x2 hi = __builtin_amdgcn_cvt_pk_f32_fp8(q1[t], true);
            a[t * 4 + 0] += lo.x; a[t * 4 + 1] += lo.y;
            a[t * 4 + 2] += hi.x; a[t * 4 + 3] += hi.y;
        }
    }
    if (j < e) {
        int i0 = csr[j];
        uint4 r0 = *(const uint4*)&X8[(size_t)i0 * C + il * 16];
        const unsigned int* q0 = (const unsigned int*)&r0;
        #pragma unroll
        for (int t = 0; t < 4; ++t) {
            f32x2 lo = __builtin_amdgcn_cvt_pk_f32_fp8(q0[t], false);
            f32x2 hi = __builtin_amdgcn_cvt_pk_f32_fp8(q0[t], true);
            a[t * 4 + 0] += lo.x; a[t * 4 + 1] += lo.y;
            a[t * 4 + 2] += hi.x; a[t * 4 + 3] += hi.y;
        }
    }

    #pragma unroll
    for (int m = GL; m < 64; m <<= 1)
        #pragma unroll
        for (int t = 0; t < 16; ++t) a[t] += __shfl_xor(a[t], m, 64);

    if (g == 0) {
        float inv = 1.0f / (float)max(e - s, 1);
        uint4 o0, o1;
        unsigned short* p0 = (unsigned short*)&o0;
        unsigned short* p1 = (unsigned short*)&o1;
        #pragma unroll
        for (int t = 0; t < 8; ++t) p0[t] = f2b(a[t] * inv);
        #pragma unroll
        for (int t = 0; t < 8; ++t) p1[t] = f2b(a[8 + t] * inv);
        *(uint4*)&out[(size_t)w * C + il * 16] = o0;
        *(uint4*)&out[(size_t)w * C + il * 16 + 8] = o1;
    }
}

// pool: bf16 input [N,256] -> fp32 pooled [G,256]; one wave per graph
__global__ void pool_mean_k(const unsigned short* __restrict__ H, const int* __restrict__ gofs,
                            float* __restrict__ pooled, int G) {
    int g = (int)((blockIdx.x * blockDim.x + threadIdx.x) >> 6);
    int lane = threadIdx.x & 63;
    if (g >= G) return;
    int s = gofs[g], e = gofs[g + 1];
    float a0 = 0.f, a1 = 0.f, a2 = 0.f, a3 = 0.f;
    for (int r = s; r < e; ++r) {
        ushort4 t = ((const ushort4*)(H + (size_t)r * HID))[lane];
        a0 += b2f(t.x); a1 += b2f(t.y); a2 += b2f(t.z); a3 += b2f(t.w);
    }
    float inv = 1.0f / (float)max(e - s, 1);
    float4 o; o.x = a0 * inv; o.y = a1 * inv; o.z = a2 * inv; o.w = a3 * inv;
    ((float4*)(pooled + (size_t)g * HID))[lane] = o;
}

// ---------------------------------------------------------------- bf16 MFMA GEMM
// 128x128 tile, 4 waves 2x2, each wave 4x4 frags of 16x16x32, BK=32.
// Double-buffered LDS; global_load_lds prefetch held across raw barriers.
// Staging uses the R9 lane mapping (consecutive lanes -> contiguous 16B): the
// global_load_lds coalescer is lane-order-sensitive [measured R9 vs R10/R11:
// 84 vs 104/99 us]; the resulting 8-way LDS read conflict is amortized.
// Optional f8out: epilogue also emits fp8-e4m3 mirror of C (fuses b2f8).
__launch_bounds__(256)
__global__ void mfma_gemm_k(const unsigned short* __restrict__ A1, int K1,
                            const unsigned short* __restrict__ A2, int K2,
                            const unsigned short* __restrict__ Bt,
                            const float* __restrict__ bias, int M, int Nfull,
                            void* __restrict__ Cptr, unsigned char* __restrict__ f8out,
                            int c_bf16, int do_relu) {
    __shared__ short ldsA[2 * 4096];
    __shared__ short ldsB[2 * 4096];
    int tid = threadIdx.x, lane = tid & 63;
    int wid = tid >> 6, wm = wid >> 1, wn = wid & 1;
    int row0 = blockIdx.x * 128, col0 = blockIdx.y * 128;
    int q = lane >> 4, l15 = lane & 15;
    int KT = K1 + K2;
    int nk = KT / 32;

    int rr = tid >> 2;            // 0..63 row within half-tile (lane-contiguous chunks)
    int c8 = (tid & 3) * 8;       // k-chunk offset (shorts)
    int dof = wid * 512;          // wave-uniform LDS base (shorts) per half

    auto stage = [&](int t) {
        int kt = t * 32;
        const unsigned short* Asrc; int kk, Ks;
        if (kt < K1) { Asrc = A1; kk = kt; Ks = K1; }
        else         { Asrc = A2; kk = kt - K1; Ks = K2; }
        short* bA = ldsA + (t & 1) * 4096;
        short* bB = ldsB + (t & 1) * 4096;
        #pragma unroll
        for (int h = 0; h < 2; ++h) {
            int r = h * 64 + rr;
            int gr = min(row0 + r, M - 1);
            GLOAD_LDS16(Asrc + (size_t)gr * Ks + kk + c8, bA + h * 2048 + dof);
            GLOAD_LDS16(Bt + (size_t)(col0 + r) * KT + kt + c8, bB + h * 2048 + dof);
        }
    };

    f32x4 acc[4][4] = {};

    stage(0);
    stage(1);

    for (int t = 0; t < nk; ++t) {
        if (t == nk - 1) asm volatile("s_waitcnt vmcnt(0)" ::: "memory");
        else             asm volatile("s_waitcnt vmcnt(4)" ::: "memory");
        asm volatile("s_barrier" ::: "memory");   // tile t visible to all waves

        const short* bA = ldsA + (t & 1) * 4096;
        const short* bB = ldsB + (t & 1) * 4096;
        bf16x8 af[4], bfr[4];
        #pragma unroll
        for (int i = 0; i < 4; ++i)
            af[i] = *(const bf16x8*)&bA[(wm * 64 + i * 16 + l15) * 32 + q * 8];
        #pragma unroll
        for (int j = 0; j < 4; ++j)
            bfr[j] = *(const bf16x8*)&bB[(wn * 64 + j * 16 + l15) * 32 + q * 8];
        #pragma unroll
        for (int i = 0; i < 4; ++i)
            #pragma unroll
            for (int j = 0; j < 4; ++j)
                acc[i][j] = __builtin_amdgcn_mfma_f32_16x16x32_bf16(af[i], bfr[j], acc[i][j], 0, 0, 0);

        asm volatile("s_barrier" ::: "memory");   // all waves done reading buf
        if (t + 2 < nk) stage(t + 2);             // refill the buffer just consumed
    }

    // epilogue: D layout col=lane&15, row=quad*4+reg
    #pragma unroll
    for (int i = 0; i < 4; ++i) {
        #pragma unroll
        for (int reg = 0; reg < 4; ++reg) {
            int r = row0 + wm * 64 + i * 16 + q * 4 + reg;
            if (r < M) {
                #pragma unroll
                for (int j = 0; j < 4; ++j) {
                    int cc = col0 + wn * 64 + j * 16 + l15;
                    float v = acc[i][j][reg] + bias[cc];
                    if (do_relu) v = fmaxf(v, 0.f);
                    if (c_bf16) ((unsigned short*)Cptr)[(size_t)r * Nfull + cc] = f2b(v);
                    else        ((float*)Cptr)[(size_t)r * Nfull + cc] = v;
                    if (f8out) {
                        int w8 = __builtin_amdgcn_cvt_pk_fp8_f32(v, v, 0, false);
                        f8out[(size_t)r * Nfull + cc] = (unsigned char)(w8 & 0xFF);
                    }
                }
            }
        }
    }
}

// ---------------------------------------------------------------- fp32 GEMM (head only)
#define BM_ 64
#define BK_ 16

template <int BN_>
__launch_bounds__(256)
__global__ void gemm2_k(const float* __restrict__ A1, const float* __restrict__ B1, int K1,
                        const float* __restrict__ bias, float* __restrict__ C,
                        int M, int N, int do_relu) {
    constexpr int TCOLS = BN_ / 8;
    constexpr int TROWS = 256 / TCOLS;
    constexpr int TM = BM_ / TROWS;
    __shared__ float As[BK_][BM_ + 4];
    __shared__ float Bs[BK_][BN_ + 4];
    int tid = threadIdx.x;
    int row0 = blockIdx.x * BM_;
    int col0 = blockIdx.y * BN_;
    int tx = tid % TCOLS, ty = tid / TCOLS;

    float acc[TM][8];
    #pragma unroll
    for (int i = 0; i < TM; ++i)
        #pragma unroll
        for (int j = 0; j < 8; ++j) acc[i][j] = 0.f;

    int ar = tid >> 2;
    int ak = (tid & 3) * 4;

    for (int kt = 0; kt < K1; kt += BK_) {
        {
            int r = row0 + ar;
            int rc = min(r, M - 1);
            float4 v = *(const float4*)(A1 + (size_t)rc * K1 + kt + ak);
            As[ak + 0][ar] = v.x;
            As[ak + 1][ar] = v.y;
            As[ak + 2][ar] = v.z;
            As[ak + 3][ar] = v.w;
        }
        {
            #pragma unroll
            for (int h = 0; h < BN_ / 64; ++h) {
                int idx = h * 256 + tid;
                int kr = idx / (BN_ / 4);
                int c4 = idx % (BN_ / 4);
                float4 v = *(const float4*)(B1 + (size_t)(kt + kr) * N + col0 + c4 * 4);
                *(float4*)&Bs[kr][c4 * 4] = v;
            }
        }
        __syncthreads();

        #pragma unroll
        for (int k = 0; k < BK_; ++k) {
            float a[TM], b[8];
            #pragma unroll
            for (int v = 0; v < TM / 4; ++v)
                *(float4*)&a[v * 4] = *(const float4*)&As[k][ty * TM + v * 4];
            *(float4*)&b[0] = *(const float4*)&Bs[k][tx * 8];
            *(float4*)&b[4] = *(const float4*)&Bs[k][tx * 8 + 4];
            #pragma unroll
            for (int i = 0; i < TM; ++i)
                #pragma unroll
                for (int j = 0; j < 8; ++j) acc[i][j] = fmaf(a[i], b[j], acc[i][j]);
        }
        __syncthreads();
    }

    float bv[8];
    #pragma unroll
    for (int j = 0; j < 8; ++j) bv[j] = bias[col0 + tx * 8 + j];
    #pragma unroll
    for (int i = 0; i < TM; ++i) {
        int r = row0 + ty * TM + i;
        if (r < M) {
            float* cp = C + (size_t)r * N + col0 + tx * 8;
            float o[8];
            #pragma unroll
            for (int j = 0; j < 8; ++j) {
                float v = acc[i][j] + bv[j];
                o[j] = do_relu ? fmaxf(v, 0.f) : v;
            }
            *(float4*)(cp + 0) = *(float4*)&o[0];
            *(float4*)(cp + 4) = *(float4*)&o[4];
        }
    }
}

// ---------------------------------------------------------------- launcher
extern "C" void kernel_launch(void* const* d_in, const int* in_sizes, int n_in,
                              void* d_out, int out_size, void* d_ws, size_t ws_size,
                              hipStream_t stream) {
    const float* x    = (const float*)d_in[0];
    const int*   ei   = (const int*)d_in[1];
    const int*   batch= (const int*)d_in[2];
    const float* W1l  = (const float*)d_in[3];
    const float* b1   = (const float*)d_in[4];
    const float* W1r  = (const float*)d_in[5];
    const float* W2l  = (const float*)d_in[6];
    const float* b2   = (const float*)d_in[7];
    const float* W2r  = (const float*)d_in[8];
    const float* W3   = (const float*)d_in[9];
    const float* b3   = (const float*)d_in[10];
    const float* W4   = (const float*)d_in[11];
    const float* b4   = (const float*)d_in[12];
    float* out = (float*)d_out;

    const int N = N_NODES, E = N_EDGES, G = N_GRAPHS;
    const int* src = ei;
    const int* dst = ei + E;

    char* ws = (char*)d_ws;
    size_t off = 0;
    auto alloc = [&](size_t bytes) -> char* {
        off = (off + 255) & ~(size_t)255;
        char* p = ws + off;
        off += bytes;
        return p;
    };
    int* bcnt    = (int*)alloc((size_t)NBUK * 4);
    int* bcur    = (int*)alloc((size_t)NBUK * 4);
    size_t zero_span = (size_t)((char*)(bcur + NBUK) - (char*)bcnt);
    int* bbase   = (int*)alloc((size_t)(NBUK + 1) * 4);
    int* bsums   = (int*)alloc(256 * 4);
    int* row_ofs = (int*)alloc((size_t)(N + 1) * 4);
    int* gofs    = (int*)alloc((size_t)(G + 1) * 4);
    uint2* staging = (uint2*)alloc((size_t)E * 8);
    int* csr     = (int*)alloc((size_t)E * 4);
    unsigned short* xb    = (unsigned short*)alloc((size_t)N * IN_CH * 2);
    unsigned short* mean1 = (unsigned short*)alloc((size_t)N * IN_CH * 2);
    unsigned short* h1    = (unsigned short*)alloc((size_t)N * HID * 2);
    unsigned short* mean2 = (unsigned short*)alloc((size_t)N * HID * 2);
    unsigned short* h2    = xb;  // xb+mean1 contiguous span reused for h2 [N,256]
    unsigned char*  x8    = (unsigned char*)alloc((size_t)N * IN_CH);
    unsigned char*  h1f8  = (unsigned char*)alloc((size_t)N * HID);
    unsigned short* W1T   = (unsigned short*)alloc((size_t)HID * (IN_CH + IN_CH) * 2);
    unsigned short* W2T   = (unsigned short*)alloc((size_t)HID * (HID + HID) * 2);
    float* pooled = (float*)alloc((size_t)G * HID * 4);
    float* hidden = (float*)alloc((size_t)G * HID * 4);
    (void)ws_size;

    hipMemsetAsync(bcnt, 0, zero_span, stream);

    const int EB = (E + CHUNK - 1) / CHUNK;  // 196
    bucket_count_k<<<EB, 256, 0, stream>>>(dst, bcnt, E);
    scan1_k<<<1, 256, 0, stream>>>(bcnt, bbase, bsums, NBUK);
    scan2_k<<<1, 256, 0, stream>>>(bsums, 1, bbase + NBUK);
    bin_scatter_k<<<EB, 256, 0, stream>>>(src, dst, bbase, bcur, staging, E);
    csr_build_k<<<NBUK, 256, 0, stream>>>(staging, bbase, row_ofs, csr);

    gofs_search_k<<<(G + 256) / 256, 256, 0, stream>>>(batch, gofs, N, G);

    wt_concat_k<<<(HID * 2 * IN_CH + 255) / 256, 256, 0, stream>>>(W1l, W1r, W1T, IN_CH, IN_CH, HID);
    wt_concat_k<<<(HID * 2 * HID + 255) / 256, 256, 0, stream>>>(W2l, W2r, W2T, HID, HID, HID);
    f2b8_k<<<(int)(((size_t)N * IN_CH / 8 + 255) / 256), 256, 0, stream>>>(
        x, xb, x8, (size_t)N * IN_CH / 8);

    const int MB = (N + 127) / 128;

    // layer 1: mean1 = mean-agg(x8) [fp8 gather]
    //          h1 = relu([mean1|xb] @ W1T^T + b1)  (epilogue also emits h1f8)
    agg_f8_k<IN_CH><<<(N + 3) / 4, 256, 0, stream>>>(x8, row_ofs, csr, mean1, N);
    mfma_gemm_k<<<dim3(MB, HID / 128), 256, 0, stream>>>(
        mean1, IN_CH, xb, IN_CH, W1T, b1, N, HID, h1, h1f8, 1, 1);

    // layer 2: mean2 = mean-agg(h1f8) [fp8 gather]; h2 = relu([mean2|h1] @ W2T^T + b2)
    agg_f8_k<HID><<<(N + 3) / 4, 256, 0, stream>>>(h1f8, row_ofs, csr, mean2, N);
    mfma_gemm_k<<<dim3(MB, HID / 128), 256, 0, stream>>>(
        mean2, HID, h1, HID, W2T, b2, N, HID, h2, nullptr, 1, 1);

    // global mean pool (bf16 in, fp32 out)
    pool_mean_k<<<(G + 3) / 4, 256, 0, stream>>>(h2, gofs, pooled, G);

    // MLP head (fp32)
    gemm2_k<HID><<<dim3(G / BM_, 1), 256, 0, stream>>>(
        pooled, W3, HID, b3, hidden, G, HID, 1);
    gemm2_k<OUT_CH><<<dim3(G / BM_, 1), 256, 0, stream>>>(
        hidden, W4, HID, b4, out, G, OUT_CH, 0);
}